// Round 3
// baseline (270.243 us; speedup 1.0000x reference)
//
#include <hip/hip_runtime.h>
#include <stdint.h>

// ---------------- problem constants ----------------
constexpr int Wd  = 640;
constexpr int Hd  = 480;
constexpr int Bd  = 8;
constexpr int Gd  = 368640;          // int(B*H*W*0.15)
constexpr int Nd  = Bd * Gd;         // 2,949,120
constexpr int HWd = Hd * Wd;         // 307200
constexpr int GRIDP = HWd / 256;     // 1200
constexpr int GRID2 = (Gd * 2) / 256;// 2880  (2 threads per group: 4 batches each)
constexpr int GRIDH = 1440;

// ---------------- workspace layout (bytes) ----------------
#define WS_SUM_ALL  0      // double: sum of all masked L
#define WS_SUM_LESS 8      // double: sum of masked L with top12 < bin1
#define WS_N        16     // u32: masked count
#define WS_DROP     20     // u32: n >> 2
#define WS_BIN1     24     // u32
#define WS_TGT1     28     // u32: rank within bin1
#define WS_DONE1    32     // u32: k_compute completion counter
#define WS_DONE2    36     // u32: k_hist2 completion counter
#define HIST1_OFF   64                      // 4096 u32 (top 12 bits)
#define H2C_OFF     (HIST1_OFF + 4096*4)    // 4096 u32
#define H2S_OFF     (H2C_OFF  + 4096*4)     // 4096 double
#define CTRL_BYTES  (H2S_OFF  + 4096*8)     // 65600
#define CTRL_WORDS  (CTRL_BYTES / 4)        // 16400
#define PACK_OFF    65664                   // float pk[HWd][16], 64B/pixel
#define LM_OFF      (PACK_OFF + HWd*16*4)   // float Lm[Nd]

// ---------------- kernel 0: repack depth (pixel-major, batch-minor) + zero ctrl ----------------
__global__ __launch_bounds__(256) void k_pack(const float* __restrict__ gt,
                                              const float* __restrict__ pd,
                                              unsigned char* __restrict__ ws)
{
    const int o = blockIdx.x * 256 + threadIdx.x;
    float v[16];
#pragma unroll
    for (int b = 0; b < Bd; ++b) {
        v[2 * b]     = gt[b * HWd + o];
        v[2 * b + 1] = pd[b * HWd + o];
    }
    float4* __restrict__ dst = (float4*)(ws + PACK_OFF) + (size_t)o * 4;
#pragma unroll
    for (int c = 0; c < 4; ++c)
        dst[c] = make_float4(v[4 * c], v[4 * c + 1], v[4 * c + 2], v[4 * c + 3]);

    if (blockIdx.x == 0) {
        unsigned* __restrict__ ctrl = (unsigned*)ws;
        for (int k = threadIdx.x; k < CTRL_WORDS; k += 256) ctrl[k] = 0u;
    }
}

// ---------------- kernel 1: per-sample L + mask + hist1 (+ fused sel1 in last block) ----------------
// thread layout: g = blockIdx*128 + (t&127), half = t>>7 ; handles batches half*4..half*4+3
__global__ __launch_bounds__(256, 8) void k_compute(
    const int* __restrict__ p1x, const int* __restrict__ p1y,
    const int* __restrict__ p2x, const int* __restrict__ p2y,
    const int* __restrict__ p3x, const int* __restrict__ p3y,
    unsigned char* __restrict__ ws)
{
    __shared__ unsigned lh[4096];
    __shared__ double   wsum[4];
    __shared__ unsigned wcnt[4];
    __shared__ int      lastflag;
    const int t = threadIdx.x;
    for (int k = t; k < 4096; k += 256) lh[k] = 0u;
    __syncthreads();

    const int g    = blockIdx.x * 128 + (t & 127);
    const int half = t >> 7;
    const int x1 = p1x[g], y1 = p1y[g];
    const int x2 = p2x[g], y2 = p2y[g];
    const int x3 = p3x[g], y3 = p3y[g];
    const int o1 = y1 * Wd + x1, o2 = y2 * Wd + x2, o3 = y3 * Wd + x3;
    const float u1 = (float)x1 - 320.0f, v1 = (float)y1 - 240.0f;
    const float u2 = (float)x2 - 320.0f, v2 = (float)y2 - 240.0f;
    const float u3 = (float)x3 - 320.0f, v3 = (float)y3 - 240.0f;
    constexpr float RF = 1.0f / 519.0f;

    // 32B (half a pixel line) per sample point: 4 batches' (gt,pd)
    const float4* __restrict__ pk4 = (const float4*)(ws + PACK_OFF);
    float4 A[2], Bv[2], Cv[2];
#pragma unroll
    for (int c = 0; c < 2; ++c) {
        A[c]  = pk4[(size_t)o1 * 4 + half * 2 + c];
        Bv[c] = pk4[(size_t)o2 * 4 + half * 2 + c];
        Cv[c] = pk4[(size_t)o3 * 4 + half * 2 + c];
    }
    const float* __restrict__ P1 = (const float*)A;
    const float* __restrict__ P2 = (const float*)Bv;
    const float* __restrict__ P3 = (const float*)Cv;

    float* __restrict__ Lm = (float*)(ws + LM_OFF);
    double   lsum = 0.0;
    unsigned lcnt = 0u;

#pragma unroll
    for (int j = 0; j < 4; ++j) {
        const float d1 = P1[2 * j], e1 = P1[2 * j + 1];
        const float d2 = P2[2 * j], e2 = P2[2 * j + 1];
        const float d3 = P3[2 * j], e3 = P3[2 * j + 1];

        const float a1 = fabsf(d1) * RF, a2 = fabsf(d2) * RF, a3 = fabsf(d3) * RF;
        const float gx1 = u1 * a1, gy1 = v1 * a1;
        const float gx2 = u2 * a2, gy2 = v2 * a2;
        const float gx3 = u3 * a3, gy3 = v3 * a3;

        const float D0x = gx2 - gx1, D0y = gy2 - gy1, D0z = d2 - d1;
        const float D1x = gx3 - gx1, D1y = gy3 - gy1, D1z = d3 - d1;
        const float D2x = gx3 - gx2, D2y = gy3 - gy2, D2z = d3 - d2;

        const float e00 = D0x*D0x + D0y*D0y + D0z*D0z;
        const float e11 = D1x*D1x + D1y*D1y + D1z*D1z;
        const float e22 = D2x*D2x + D2y*D2y + D2z*D2z;
        const float e01 = D0x*D1x + D0y*D1y + D0z*D1z;
        const float e02 = D0x*D2x + D0y*D2y + D0z*D2z;
        const float e12 = D1x*D2x + D1y*D2y + D1z*D2z;
        const float n0 = sqrtf(e00), n1 = sqrtf(e11), n2 = sqrtf(e22);
        constexpr float DC = 0.867f;
        int cnt = 0;
        cnt += (fabsf(e00) > DC * (n0*n0 + 1e-8f));
        cnt += (fabsf(e11) > DC * (n1*n1 + 1e-8f));
        cnt += (fabsf(e22) > DC * (n2*n2 + 1e-8f));
        cnt += 2 * (fabsf(e01) > DC * (n0*n1 + 1e-8f));
        cnt += 2 * (fabsf(e02) > DC * (n0*n2 + 1e-8f));
        cnt += 2 * (fabsf(e12) > DC * (n1*n2 + 1e-8f));
        const bool mask_cos = cnt > 3;

        const bool mx = (fabsf(D0x) < 0.01f) | (fabsf(D1x) < 0.01f) | (fabsf(D2x) < 0.01f);
        const bool my = (fabsf(D0y) < 0.01f) | (fabsf(D1y) < 0.01f) | (fabsf(D2y) < 0.01f);
        const bool mz = (fabsf(D0z) < 0.01f) | (fabsf(D1z) < 0.01f) | (fabsf(D2z) < 0.01f);
        const bool mask = !((mx && my && mz) || mask_cos);

        const float b1s = fabsf(e1) * RF, b2s = fabsf(e2) * RF, b3s = fabsf(e3) * RF;
        float qx1 = u1 * b1s, qy1 = v1 * b1s, qz1 = e1;
        float qx2 = u2 * b2s, qy2 = v2 * b2s, qz2 = e2;
        float qx3 = u3 * b3s, qy3 = v3 * b3s, qz3 = e3;
        // reference's zmask broadcast: coordinate ROW c of all points
        const bool zm0 = (qz1 == 0.0f), zm1 = (qz2 == 0.0f), zm2 = (qz3 == 0.0f);
        if (zm0) { qx1 = qx2 = qx3 = 1e-4f; }
        if (zm1) { qy1 = qy2 = qy3 = 1e-4f; }
        if (zm2) { qz1 = qz2 = qz3 = 1e-4f; }

        const float P0x = qx2 - qx1, P0y = qy2 - qy1, P0z = qz2 - qz1;
        const float Q1x = qx3 - qx1, Q1y = qy3 - qy1, Q1z = qz3 - qz1;

        const float gnx = D0y * D1z - D0z * D1y;
        const float gny = D0z * D1x - D0x * D1z;
        const float gnz = D0x * D1y - D0y * D1x;
        const float dnx = P0y * Q1z - P0z * Q1y;
        const float dny = P0z * Q1x - P0x * Q1z;
        const float dnz = P0x * Q1y - P0y * Q1x;

        float gnn = sqrtf(gnx*gnx + gny*gny + gnz*gnz);
        float dnn = sqrtf(dnx*dnx + dny*dny + dnz*dnz);
        if (gnn == 0.0f) gnn = 0.01f;
        if (dnn == 0.0f) dnn = 0.01f;
        const float rg = 1.0f / gnn, rd = 1.0f / dnn;
        const float L = fabsf(gnx*rg - dnx*rd) + fabsf(gny*rg - dny*rd) + fabsf(gnz*rg - dnz*rd);

        Lm[(half * 4 + j) * Gd + g] = mask ? L : -1.0f;
        if (mask) {
            ++lcnt;
            lsum += (double)L;
            atomicAdd(&lh[__float_as_uint(L) >> 20], 1u);
        }
    }

    // wave shuffle reduction, then 1 global atomic pair per block
#pragma unroll
    for (int off = 32; off > 0; off >>= 1) {
        lsum += __shfl_down(lsum, off);
        lcnt += __shfl_down(lcnt, off);
    }
    if ((t & 63) == 0) { wsum[t >> 6] = lsum; wcnt[t >> 6] = lcnt; }
    __syncthreads();
    if (t == 0) {
        atomicAdd((double*)(ws + WS_SUM_ALL), wsum[0] + wsum[1] + wsum[2] + wsum[3]);
        atomicAdd((unsigned*)(ws + WS_N), wcnt[0] + wcnt[1] + wcnt[2] + wcnt[3]);
    }
    unsigned* __restrict__ h1 = (unsigned*)(ws + HIST1_OFF);
    for (int k = t; k < 4096; k += 256) {
        const unsigned c = lh[k];
        if (c) atomicAdd(&h1[k], c);
    }

    // ---- fused sel1: last block to finish selects the top-12-bit bin ----
    __syncthreads();
    if (t == 0) {
        __threadfence();
        lastflag = (atomicAdd((unsigned*)(ws + WS_DONE1), 1u) == (unsigned)(gridDim.x - 1));
    }
    __syncthreads();
    if (!lastflag) return;

    const unsigned n = __hip_atomic_load((const unsigned*)(ws + WS_N),
                                         __ATOMIC_RELAXED, __HIP_MEMORY_SCOPE_AGENT);
    const unsigned drop = n >> 2;
    if (t == 0) *(unsigned*)(ws + WS_DROP) = drop;
    if (drop == 0) {
        if (t == 0) { *(unsigned*)(ws + WS_BIN1) = 0xFFFFFFFFu; *(unsigned*)(ws + WS_TGT1) = 0u; }
        return;
    }
    unsigned loc[16]; unsigned s = 0;
#pragma unroll
    for (int k = 0; k < 16; ++k) {
        loc[k] = __hip_atomic_load(&h1[t * 16 + k], __ATOMIC_RELAXED, __HIP_MEMORY_SCOPE_AGENT);
        s += loc[k];
    }
    unsigned* part = lh;   // reuse LDS
    part[t] = s;
    __syncthreads();
    for (int off = 1; off < 256; off <<= 1) {
        const unsigned add = (t >= off) ? part[t - off] : 0u;
        __syncthreads();
        part[t] += add;
        __syncthreads();
    }
    const unsigned incl = part[t];
    const unsigned excl = incl - s;
    if (incl >= drop && excl < drop) {
        unsigned cum = excl;
#pragma unroll
        for (int k = 0; k < 16; ++k) {
            const unsigned c = loc[k];
            if (cum + c >= drop) {
                *(unsigned*)(ws + WS_BIN1) = (unsigned)(t * 16 + k);
                *(unsigned*)(ws + WS_TGT1) = drop - cum;
                break;
            }
            cum += c;
        }
    }
}

// ---------------- kernel 2: hist2 within bin1 + sum_less (+ fused sel2/finalize) ----------------
__global__ __launch_bounds__(256) void k_hist2(unsigned char* __restrict__ ws,
                                               float* __restrict__ out)
{
    __shared__ unsigned c2[4096];
    __shared__ float    s2[4096];
    __shared__ double   red[4];
    __shared__ double   ps[256];
    __shared__ int      lastflag;
    const int t = threadIdx.x;
    for (int k = t; k < 4096; k += 256) { c2[k] = 0u; s2[k] = 0.0f; }
    __syncthreads();

    const unsigned bin1 = *(const unsigned*)(ws + WS_BIN1);   // written by prev kernel
    const float* __restrict__ Lm = (const float*)(ws + LM_OFF);
    const int stride = gridDim.x * 256;
    double dless = 0.0;
    for (int i = blockIdx.x * 256 + t; i < Nd; i += stride) {
        const unsigned u = __float_as_uint(Lm[i]);
        if (u & 0x80000000u) continue;
        const unsigned top = u >> 20;
        if (top < bin1) {
            dless += (double)__uint_as_float(u);
        } else if (top == bin1) {
            const int k = (u >> 8) & 0xFFF;
            atomicAdd(&c2[k], 1u);
            atomicAdd(&s2[k], __uint_as_float(u));
        }
    }
#pragma unroll
    for (int off = 32; off > 0; off >>= 1) dless += __shfl_down(dless, off);
    if ((t & 63) == 0) red[t >> 6] = dless;
    __syncthreads();
    if (t == 0) atomicAdd((double*)(ws + WS_SUM_LESS), red[0] + red[1] + red[2] + red[3]);

    unsigned* __restrict__ gc = (unsigned*)(ws + H2C_OFF);
    double*   __restrict__ gs = (double*)(ws + H2S_OFF);
    for (int k = t; k < 4096; k += 256) {
        const unsigned c = c2[k];
        if (c) { atomicAdd(&gc[k], c); atomicAdd(&gs[k], (double)s2[k]); }
    }

    // ---- fused sel2 + finalize in last block ----
    __syncthreads();
    if (t == 0) {
        __threadfence();
        lastflag = (atomicAdd((unsigned*)(ws + WS_DONE2), 1u) == (unsigned)(gridDim.x - 1));
    }
    __syncthreads();
    if (!lastflag) return;

    const unsigned n    = *(const unsigned*)(ws + WS_N);
    const unsigned drop = *(const unsigned*)(ws + WS_DROP);
    const double sum_all = *(const double*)(ws + WS_SUM_ALL);
    const unsigned keep = n - drop;
    const double denom = (double)(keep > 0u ? keep : 1u);

    if (drop == 0) {
        if (t == 0) out[0] = (float)(sum_all / denom);
        return;
    }
    const unsigned tgt1 = *(const unsigned*)(ws + WS_TGT1);
    const double sum_less = __hip_atomic_load((const double*)(ws + WS_SUM_LESS),
                                              __ATOMIC_RELAXED, __HIP_MEMORY_SCOPE_AGENT);
    unsigned lc[16]; double lsv[16];
    unsigned cs = 0; double ss = 0.0;
#pragma unroll
    for (int k = 0; k < 16; ++k) {
        lc[k]  = __hip_atomic_load(&gc[t * 16 + k], __ATOMIC_RELAXED, __HIP_MEMORY_SCOPE_AGENT);
        lsv[k] = __hip_atomic_load(&gs[t * 16 + k], __ATOMIC_RELAXED, __HIP_MEMORY_SCOPE_AGENT);
        cs += lc[k]; ss += lsv[k];
    }
    unsigned* pc = c2;   // reuse LDS
    pc[t] = cs; ps[t] = ss;
    __syncthreads();
    for (int off = 1; off < 256; off <<= 1) {
        const unsigned addc = (t >= off) ? pc[t - off] : 0u;
        const double   adds = (t >= off) ? ps[t - off] : 0.0;
        __syncthreads();
        pc[t] += addc; ps[t] += adds;
        __syncthreads();
    }
    const unsigned inclc = pc[t];
    const unsigned exclc = inclc - cs;
    if (inclc >= tgt1 && exclc < tgt1) {
        unsigned cum = exclc;
        double scum = ps[t] - ss;
        for (int k = 0; k < 16; ++k) {
            const unsigned c = lc[k];
            if (cum + c >= tgt1) {
                const unsigned bin2 = (unsigned)(t * 16 + k);
                const unsigned tgt2 = tgt1 - cum;
                const float v_lo = __uint_as_float((bin1 << 20) | (bin2 << 8));
                const double dropped = sum_less + scum + (double)tgt2 * (double)v_lo;
                out[0] = (float)((sum_all - dropped) / denom);
                break;
            }
            cum += c;
            scum += lsv[k];
        }
    }
}

extern "C" void kernel_launch(void* const* d_in, const int* in_sizes, int n_in,
                              void* d_out, int out_size, void* d_ws, size_t ws_size,
                              hipStream_t stream)
{
    const float* gt  = (const float*)d_in[0];
    const float* pd  = (const float*)d_in[1];
    const int*   p1x = (const int*)d_in[2];
    const int*   p1y = (const int*)d_in[3];
    const int*   p2x = (const int*)d_in[4];
    const int*   p2y = (const int*)d_in[5];
    const int*   p3x = (const int*)d_in[6];
    const int*   p3y = (const int*)d_in[7];
    unsigned char* ws = (unsigned char*)d_ws;
    float* out = (float*)d_out;

    k_pack   <<<dim3(GRIDP), dim3(256), 0, stream>>>(gt, pd, ws);
    k_compute<<<dim3(GRID2), dim3(256), 0, stream>>>(p1x, p1y, p2x, p2y, p3x, p3y, ws);
    k_hist2  <<<dim3(GRIDH), dim3(256), 0, stream>>>(ws, out);
}

// Round 4
// 266.705 us; speedup vs baseline: 1.0133x; 1.0133x over previous
//
#include <hip/hip_runtime.h>
#include <stdint.h>

// ---------------- problem constants ----------------
constexpr int Wd  = 640;
constexpr int Hd  = 480;
constexpr int Bd  = 8;
constexpr int Gd  = 368640;          // int(B*H*W*0.15)
constexpr int Nd  = Bd * Gd;         // 2,949,120
constexpr int HWd = Hd * Wd;         // 307200
constexpr int GRIDP = HWd / 256;     // 1200
constexpr int GRIDC = Gd / 128;      // 2880 blocks of 128 thr, 1 group/thread
constexpr int GRIDH = 1440;

// bit split: level-1 = top 11 bits (u>>21), level-2 = bits [20:9] (12 bits),
// leftover 9 bits approximated by bin lower edge (error <= tgt2 * 2^-14 * v).
constexpr int NB1 = 2048;

// ---------------- workspace layout (bytes) ----------------
#define WS_SUM_ALL  0      // double: sum of all masked L
#define WS_SUM_LESS 8      // double: sum of masked L with top11 < bin1
#define WS_N        16     // u32: masked count
#define WS_DROP     20     // u32: n >> 2
#define WS_BIN1     24     // u32
#define WS_TGT1     28     // u32: rank within bin1
#define WS_DONE1    32     // u32: k_compute completion counter
#define WS_DONE2    36     // u32: k_hist2 completion counter
#define HIST1_OFF   64                      // NB1 u32
#define H2C_OFF     (HIST1_OFF + NB1*4)     // 4096 u32
#define H2S_OFF     (H2C_OFF  + 4096*4)     // 4096 double
#define CTRL_BYTES  (H2S_OFF  + 4096*8)
#define CTRL_WORDS  (CTRL_BYTES / 4)
#define PACK_OFF    ((CTRL_BYTES + 255) & ~255)   // float pk[HWd][16], 64B/pixel
#define LM_OFF      (PACK_OFF + HWd*16*4)         // float Lm[Nd]

// ---------------- kernel 0: repack depth (pixel-major, batch-minor) + zero ctrl ----------------
__global__ __launch_bounds__(256) void k_pack(const float* __restrict__ gt,
                                              const float* __restrict__ pd,
                                              unsigned char* __restrict__ ws)
{
    const int o = blockIdx.x * 256 + threadIdx.x;
    float v[16];
#pragma unroll
    for (int b = 0; b < Bd; ++b) {
        v[2 * b]     = gt[b * HWd + o];
        v[2 * b + 1] = pd[b * HWd + o];
    }
    float4* __restrict__ dst = (float4*)(ws + PACK_OFF) + (size_t)o * 4;
#pragma unroll
    for (int c = 0; c < 4; ++c)
        dst[c] = make_float4(v[4 * c], v[4 * c + 1], v[4 * c + 2], v[4 * c + 3]);

    if (blockIdx.x == 0) {
        unsigned* __restrict__ ctrl = (unsigned*)ws;
        for (int k = threadIdx.x; k < CTRL_WORDS; k += 256) ctrl[k] = 0u;
    }
}

// ---------------- kernel 1: per-sample L + mask + hist1 (+ fused sel1 in last block) ----------------
// 128 threads/block, one group per thread, all 8 batches (3x 64B packed lines).
__global__ __launch_bounds__(128) void k_compute(
    const int* __restrict__ p1x, const int* __restrict__ p1y,
    const int* __restrict__ p2x, const int* __restrict__ p2y,
    const int* __restrict__ p3x, const int* __restrict__ p3y,
    unsigned char* __restrict__ ws)
{
    __shared__ unsigned lh[NB1];
    __shared__ double   wsum[2];
    __shared__ unsigned wcnt[2];
    __shared__ unsigned part[128];
    __shared__ int      lastflag;
    const int t = threadIdx.x;
    for (int k = t; k < NB1; k += 128) lh[k] = 0u;
    __syncthreads();

    const int g = blockIdx.x * 128 + t;
    const int x1 = p1x[g], y1 = p1y[g];
    const int x2 = p2x[g], y2 = p2y[g];
    const int x3 = p3x[g], y3 = p3y[g];
    const int o1 = y1 * Wd + x1, o2 = y2 * Wd + x2, o3 = y3 * Wd + x3;
    const float u1 = (float)x1 - 320.0f, v1 = (float)y1 - 240.0f;
    const float u2 = (float)x2 - 320.0f, v2 = (float)y2 - 240.0f;
    const float u3 = (float)x3 - 320.0f, v3 = (float)y3 - 240.0f;
    constexpr float RF = 1.0f / 519.0f;

    // 3 random 64B lines, issued as 12 independent float4 loads (max MLP)
    const float4* __restrict__ pk4 = (const float4*)(ws + PACK_OFF);
    float4 A[4], Bv[4], Cv[4];
#pragma unroll
    for (int c = 0; c < 4; ++c) {
        A[c]  = pk4[(size_t)o1 * 4 + c];
        Bv[c] = pk4[(size_t)o2 * 4 + c];
        Cv[c] = pk4[(size_t)o3 * 4 + c];
    }
    const float* __restrict__ P1 = (const float*)A;
    const float* __restrict__ P2 = (const float*)Bv;
    const float* __restrict__ P3 = (const float*)Cv;

    float* __restrict__ Lm = (float*)(ws + LM_OFF);
    double   lsum = 0.0;
    unsigned lcnt = 0u;

#pragma unroll
    for (int b = 0; b < Bd; ++b) {
        const float d1 = P1[2 * b], e1 = P1[2 * b + 1];
        const float d2 = P2[2 * b], e2 = P2[2 * b + 1];
        const float d3 = P3[2 * b], e3 = P3[2 * b + 1];

        const float a1 = fabsf(d1) * RF, a2 = fabsf(d2) * RF, a3 = fabsf(d3) * RF;
        const float gx1 = u1 * a1, gy1 = v1 * a1;
        const float gx2 = u2 * a2, gy2 = v2 * a2;
        const float gx3 = u3 * a3, gy3 = v3 * a3;

        const float D0x = gx2 - gx1, D0y = gy2 - gy1, D0z = d2 - d1;
        const float D1x = gx3 - gx1, D1y = gy3 - gy1, D1z = d3 - d1;
        const float D2x = gx3 - gx2, D2y = gy3 - gy2, D2z = d3 - d2;

        const float e00 = D0x*D0x + D0y*D0y + D0z*D0z;
        const float e11 = D1x*D1x + D1y*D1y + D1z*D1z;
        const float e22 = D2x*D2x + D2y*D2y + D2z*D2z;
        const float e01 = D0x*D1x + D0y*D1y + D0z*D1z;
        const float e02 = D0x*D2x + D0y*D2y + D0z*D2z;
        const float e12 = D1x*D2x + D1y*D2y + D1z*D2z;
        const float n0 = sqrtf(e00), n1 = sqrtf(e11), n2 = sqrtf(e22);
        constexpr float DC = 0.867f;
        int cnt = 0;
        cnt += (fabsf(e00) > DC * (n0*n0 + 1e-8f));
        cnt += (fabsf(e11) > DC * (n1*n1 + 1e-8f));
        cnt += (fabsf(e22) > DC * (n2*n2 + 1e-8f));
        cnt += 2 * (fabsf(e01) > DC * (n0*n1 + 1e-8f));
        cnt += 2 * (fabsf(e02) > DC * (n0*n2 + 1e-8f));
        cnt += 2 * (fabsf(e12) > DC * (n1*n2 + 1e-8f));
        const bool mask_cos = cnt > 3;

        const bool mx = (fabsf(D0x) < 0.01f) | (fabsf(D1x) < 0.01f) | (fabsf(D2x) < 0.01f);
        const bool my = (fabsf(D0y) < 0.01f) | (fabsf(D1y) < 0.01f) | (fabsf(D2y) < 0.01f);
        const bool mz = (fabsf(D0z) < 0.01f) | (fabsf(D1z) < 0.01f) | (fabsf(D2z) < 0.01f);
        const bool mask = !((mx && my && mz) || mask_cos);

        const float b1s = fabsf(e1) * RF, b2s = fabsf(e2) * RF, b3s = fabsf(e3) * RF;
        float qx1 = u1 * b1s, qy1 = v1 * b1s, qz1 = e1;
        float qx2 = u2 * b2s, qy2 = v2 * b2s, qz2 = e2;
        float qx3 = u3 * b3s, qy3 = v3 * b3s, qz3 = e3;
        // reference's zmask broadcast: coordinate ROW c of all points
        const bool zm0 = (qz1 == 0.0f), zm1 = (qz2 == 0.0f), zm2 = (qz3 == 0.0f);
        if (zm0) { qx1 = qx2 = qx3 = 1e-4f; }
        if (zm1) { qy1 = qy2 = qy3 = 1e-4f; }
        if (zm2) { qz1 = qz2 = qz3 = 1e-4f; }

        const float P0x = qx2 - qx1, P0y = qy2 - qy1, P0z = qz2 - qz1;
        const float Q1x = qx3 - qx1, Q1y = qy3 - qy1, Q1z = qz3 - qz1;

        const float gnx = D0y * D1z - D0z * D1y;
        const float gny = D0z * D1x - D0x * D1z;
        const float gnz = D0x * D1y - D0y * D1x;
        const float dnx = P0y * Q1z - P0z * Q1y;
        const float dny = P0z * Q1x - P0x * Q1z;
        const float dnz = P0x * Q1y - P0y * Q1x;

        float gnn = sqrtf(gnx*gnx + gny*gny + gnz*gnz);
        float dnn = sqrtf(dnx*dnx + dny*dny + dnz*dnz);
        if (gnn == 0.0f) gnn = 0.01f;
        if (dnn == 0.0f) dnn = 0.01f;
        const float rg = 1.0f / gnn, rd = 1.0f / dnn;
        const float L = fabsf(gnx*rg - dnx*rd) + fabsf(gny*rg - dny*rd) + fabsf(gnz*rg - dnz*rd);

        Lm[b * Gd + g] = mask ? L : -1.0f;
        if (mask) {
            ++lcnt;
            lsum += (double)L;
            atomicAdd(&lh[__float_as_uint(L) >> 21], 1u);
        }
    }

#pragma unroll
    for (int off = 32; off > 0; off >>= 1) {
        lsum += __shfl_down(lsum, off);
        lcnt += __shfl_down(lcnt, off);
    }
    if ((t & 63) == 0) { wsum[t >> 6] = lsum; wcnt[t >> 6] = lcnt; }
    __syncthreads();
    if (t == 0) {
        atomicAdd((double*)(ws + WS_SUM_ALL), wsum[0] + wsum[1]);
        atomicAdd((unsigned*)(ws + WS_N), wcnt[0] + wcnt[1]);
    }
    unsigned* __restrict__ h1 = (unsigned*)(ws + HIST1_OFF);
    for (int k = t; k < NB1; k += 128) {
        const unsigned c = lh[k];
        if (c) atomicAdd(&h1[k], c);
    }

    // ---- fused sel1: last block selects the top-11-bit bin ----
    __syncthreads();
    if (t == 0) {
        __threadfence();
        lastflag = (atomicAdd((unsigned*)(ws + WS_DONE1), 1u) == (unsigned)(gridDim.x - 1));
    }
    __syncthreads();
    if (!lastflag) return;

    const unsigned n = __hip_atomic_load((const unsigned*)(ws + WS_N),
                                         __ATOMIC_RELAXED, __HIP_MEMORY_SCOPE_AGENT);
    const unsigned drop = n >> 2;
    if (t == 0) *(unsigned*)(ws + WS_DROP) = drop;
    if (drop == 0) {
        if (t == 0) { *(unsigned*)(ws + WS_BIN1) = 0xFFFFFFFFu; *(unsigned*)(ws + WS_TGT1) = 0u; }
        return;
    }
    unsigned loc[16]; unsigned s = 0;
#pragma unroll
    for (int k = 0; k < 16; ++k) {
        loc[k] = __hip_atomic_load(&h1[t * 16 + k], __ATOMIC_RELAXED, __HIP_MEMORY_SCOPE_AGENT);
        s += loc[k];
    }
    part[t] = s;
    __syncthreads();
    for (int off = 1; off < 128; off <<= 1) {
        const unsigned add = (t >= off) ? part[t - off] : 0u;
        __syncthreads();
        part[t] += add;
        __syncthreads();
    }
    const unsigned incl = part[t];
    const unsigned excl = incl - s;
    if (incl >= drop && excl < drop) {
        unsigned cum = excl;
#pragma unroll
        for (int k = 0; k < 16; ++k) {
            const unsigned c = loc[k];
            if (cum + c >= drop) {
                *(unsigned*)(ws + WS_BIN1) = (unsigned)(t * 16 + k);
                *(unsigned*)(ws + WS_TGT1) = drop - cum;
                break;
            }
            cum += c;
        }
    }
}

// ---------------- kernel 2: hist2 within bin1 + sum_less (+ fused sel2/finalize) ----------------
__global__ __launch_bounds__(256) void k_hist2(unsigned char* __restrict__ ws,
                                               float* __restrict__ out)
{
    __shared__ unsigned c2[4096];
    __shared__ float    s2[4096];
    __shared__ double   red[4];
    __shared__ double   ps[256];
    __shared__ int      lastflag;
    const int t = threadIdx.x;
    for (int k = t; k < 4096; k += 256) { c2[k] = 0u; s2[k] = 0.0f; }
    __syncthreads();

    const unsigned bin1 = *(const unsigned*)(ws + WS_BIN1);
    const uint4* __restrict__ Lm4 = (const uint4*)(ws + LM_OFF);
    const int n4 = Nd / 4;
    const int stride = gridDim.x * 256;
    double dless = 0.0;
    for (int i = blockIdx.x * 256 + t; i < n4; i += stride) {
        const uint4 q = Lm4[i];
        unsigned uu[4] = {q.x, q.y, q.z, q.w};
#pragma unroll
        for (int j = 0; j < 4; ++j) {
            const unsigned u = uu[j];
            if (u & 0x80000000u) continue;
            const unsigned top = u >> 21;
            if (top < bin1) {
                dless += (double)__uint_as_float(u);
            } else if (top == bin1) {
                const int k = (u >> 9) & 0xFFF;
                atomicAdd(&c2[k], 1u);
                atomicAdd(&s2[k], __uint_as_float(u));
            }
        }
    }
#pragma unroll
    for (int off = 32; off > 0; off >>= 1) dless += __shfl_down(dless, off);
    if ((t & 63) == 0) red[t >> 6] = dless;
    __syncthreads();
    if (t == 0) atomicAdd((double*)(ws + WS_SUM_LESS), red[0] + red[1] + red[2] + red[3]);

    unsigned* __restrict__ gc = (unsigned*)(ws + H2C_OFF);
    double*   __restrict__ gs = (double*)(ws + H2S_OFF);
    for (int k = t; k < 4096; k += 256) {
        const unsigned c = c2[k];
        if (c) { atomicAdd(&gc[k], c); atomicAdd(&gs[k], (double)s2[k]); }
    }

    // ---- fused sel2 + finalize in last block ----
    __syncthreads();
    if (t == 0) {
        __threadfence();
        lastflag = (atomicAdd((unsigned*)(ws + WS_DONE2), 1u) == (unsigned)(gridDim.x - 1));
    }
    __syncthreads();
    if (!lastflag) return;

    const unsigned n    = *(const unsigned*)(ws + WS_N);
    const unsigned drop = *(const unsigned*)(ws + WS_DROP);
    const double sum_all = *(const double*)(ws + WS_SUM_ALL);
    const unsigned keep = n - drop;
    const double denom = (double)(keep > 0u ? keep : 1u);

    if (drop == 0) {
        if (t == 0) out[0] = (float)(sum_all / denom);
        return;
    }
    const unsigned tgt1 = *(const unsigned*)(ws + WS_TGT1);
    const double sum_less = __hip_atomic_load((const double*)(ws + WS_SUM_LESS),
                                              __ATOMIC_RELAXED, __HIP_MEMORY_SCOPE_AGENT);
    unsigned lc[16]; double lsv[16];
    unsigned cs = 0; double ss = 0.0;
#pragma unroll
    for (int k = 0; k < 16; ++k) {
        lc[k]  = __hip_atomic_load(&gc[t * 16 + k], __ATOMIC_RELAXED, __HIP_MEMORY_SCOPE_AGENT);
        lsv[k] = __hip_atomic_load(&gs[t * 16 + k], __ATOMIC_RELAXED, __HIP_MEMORY_SCOPE_AGENT);
        cs += lc[k]; ss += lsv[k];
    }
    unsigned* pc = c2;   // reuse LDS
    pc[t] = cs; ps[t] = ss;
    __syncthreads();
    for (int off = 1; off < 256; off <<= 1) {
        const unsigned addc = (t >= off) ? pc[t - off] : 0u;
        const double   adds = (t >= off) ? ps[t - off] : 0.0;
        __syncthreads();
        pc[t] += addc; ps[t] += adds;
        __syncthreads();
    }
    const unsigned inclc = pc[t];
    const unsigned exclc = inclc - cs;
    if (inclc >= tgt1 && exclc < tgt1) {
        unsigned cum = exclc;
        double scum = ps[t] - ss;
        for (int k = 0; k < 16; ++k) {
            const unsigned c = lc[k];
            if (cum + c >= tgt1) {
                const unsigned bin2 = (unsigned)(t * 16 + k);
                const unsigned tgt2 = tgt1 - cum;
                const float v_lo = __uint_as_float((bin1 << 21) | (bin2 << 9));
                const double dropped = sum_less + scum + (double)tgt2 * (double)v_lo;
                out[0] = (float)((sum_all - dropped) / denom);
                break;
            }
            cum += c;
            scum += lsv[k];
        }
    }
}

extern "C" void kernel_launch(void* const* d_in, const int* in_sizes, int n_in,
                              void* d_out, int out_size, void* d_ws, size_t ws_size,
                              hipStream_t stream)
{
    const float* gt  = (const float*)d_in[0];
    const float* pd  = (const float*)d_in[1];
    const int*   p1x = (const int*)d_in[2];
    const int*   p1y = (const int*)d_in[3];
    const int*   p2x = (const int*)d_in[4];
    const int*   p2y = (const int*)d_in[5];
    const int*   p3x = (const int*)d_in[6];
    const int*   p3y = (const int*)d_in[7];
    unsigned char* ws = (unsigned char*)d_ws;
    float* out = (float*)d_out;

    k_pack   <<<dim3(GRIDP), dim3(256), 0, stream>>>(gt, pd, ws);
    k_compute<<<dim3(GRIDC), dim3(128), 0, stream>>>(p1x, p1y, p2x, p2y, p3x, p3y, ws);
    k_hist2  <<<dim3(GRIDH), dim3(256), 0, stream>>>(ws, out);
}

// Round 5
// 200.902 us; speedup vs baseline: 1.3451x; 1.3275x over previous
//
#include <hip/hip_runtime.h>
#include <stdint.h>

// ---------------- problem constants ----------------
constexpr int Wd  = 640;
constexpr int Hd  = 480;
constexpr int Bd  = 8;
constexpr int Gd  = 368640;          // int(B*H*W*0.15)
constexpr int Nd  = Bd * Gd;         // 2,949,120
constexpr int HWd = Hd * Wd;         // 307200
constexpr int GRIDP = HWd / 256;     // 1200
constexpr int GRIDC = Gd / 256;      // 1440  (R2's proven-good config)
constexpr int GRIDH = 1440;

// ---------------- workspace layout (bytes) ----------------
#define WS_SUM_ALL  0      // double: sum of all masked L
#define WS_SUM_LESS 8      // double: sum of masked L with top12 < bin1
#define WS_N        16     // u32: masked count
#define WS_DROP     20     // u32: n >> 2
#define WS_BIN1     24     // u32
#define WS_TGT1     28     // u32: rank within bin1
#define WS_DONE1    32     // u32: k_compute completion counter
#define WS_DONE2    36     // u32: k_hist2 completion counter
#define HIST1_OFF   64                      // 4096 u32 (top 12 bits)
#define H2C_OFF     (HIST1_OFF + 4096*4)    // 4096 u32 (bits [19:8] within bin1)
#define H2S_OFF     (H2C_OFF  + 4096*4)     // 4096 double
#define CTRL_BYTES  (H2S_OFF  + 4096*8)
#define CTRL_WORDS  (CTRL_BYTES / 4)
#define PACK_OFF    ((CTRL_BYTES + 255) & ~255)   // float pk[HWd][16], 64B/pixel
#define LM_OFF      (PACK_OFF + HWd*16*4)         // float Lm[Nd]

// ---------------- kernel 0: repack depth (pixel-major, batch-minor) + zero ctrl ----------------
__global__ __launch_bounds__(256) void k_pack(const float* __restrict__ gt,
                                              const float* __restrict__ pd,
                                              unsigned char* __restrict__ ws)
{
    const int o = blockIdx.x * 256 + threadIdx.x;
    float v[16];
#pragma unroll
    for (int b = 0; b < Bd; ++b) {
        v[2 * b]     = gt[b * HWd + o];
        v[2 * b + 1] = pd[b * HWd + o];
    }
    float4* __restrict__ dst = (float4*)(ws + PACK_OFF) + (size_t)o * 4;
#pragma unroll
    for (int c = 0; c < 4; ++c)
        dst[c] = make_float4(v[4 * c], v[4 * c + 1], v[4 * c + 2], v[4 * c + 3]);

    if (blockIdx.x == 0) {
        unsigned* __restrict__ ctrl = (unsigned*)ws;
        for (int k = threadIdx.x; k < CTRL_WORDS; k += 256) ctrl[k] = 0u;
    }
}

// ---------------- kernel 1: per-sample L + mask + hist1 (+ FENCE-FREE fused sel1) ----------------
// 256 threads/block, one group per thread, all 8 batches (3x 64B packed lines).
// NOTE: no __threadfence() anywhere — agent-scope fences writeback+invalidate the
// XCD L2 on gfx950 (non-coherent L2s) and thrash the gather working set (R3/R4
// regression: 73 -> 138+ us). __syncthreads() already drains vmcnt(0) per wave,
// so after the barrier all this block's device-scope atomics are complete.
__global__ __launch_bounds__(256) void k_compute(
    const int* __restrict__ p1x, const int* __restrict__ p1y,
    const int* __restrict__ p2x, const int* __restrict__ p2y,
    const int* __restrict__ p3x, const int* __restrict__ p3y,
    unsigned char* __restrict__ ws)
{
    __shared__ unsigned lh[4096];
    __shared__ double   wsum[4];
    __shared__ unsigned wcnt[4];
    __shared__ int      lastflag;
    const int t = threadIdx.x;
    for (int k = t; k < 4096; k += 256) lh[k] = 0u;
    __syncthreads();

    const int g = blockIdx.x * 256 + t;
    const int x1 = p1x[g], y1 = p1y[g];
    const int x2 = p2x[g], y2 = p2y[g];
    const int x3 = p3x[g], y3 = p3y[g];
    const int o1 = y1 * Wd + x1, o2 = y2 * Wd + x2, o3 = y3 * Wd + x3;
    const float u1 = (float)x1 - 320.0f, v1 = (float)y1 - 240.0f;
    const float u2 = (float)x2 - 320.0f, v2 = (float)y2 - 240.0f;
    const float u3 = (float)x3 - 320.0f, v3 = (float)y3 - 240.0f;
    constexpr float RF = 1.0f / 519.0f;

    // 3 random 64B lines, issued as 12 independent float4 loads (max MLP)
    const float4* __restrict__ pk4 = (const float4*)(ws + PACK_OFF);
    float4 A[4], Bv[4], Cv[4];
#pragma unroll
    for (int c = 0; c < 4; ++c) {
        A[c]  = pk4[(size_t)o1 * 4 + c];
        Bv[c] = pk4[(size_t)o2 * 4 + c];
        Cv[c] = pk4[(size_t)o3 * 4 + c];
    }
    const float* __restrict__ P1 = (const float*)A;
    const float* __restrict__ P2 = (const float*)Bv;
    const float* __restrict__ P3 = (const float*)Cv;

    float* __restrict__ Lm = (float*)(ws + LM_OFF);
    double   lsum = 0.0;
    unsigned lcnt = 0u;

#pragma unroll
    for (int b = 0; b < Bd; ++b) {
        const float d1 = P1[2 * b], e1 = P1[2 * b + 1];
        const float d2 = P2[2 * b], e2 = P2[2 * b + 1];
        const float d3 = P3[2 * b], e3 = P3[2 * b + 1];

        const float a1 = fabsf(d1) * RF, a2 = fabsf(d2) * RF, a3 = fabsf(d3) * RF;
        const float gx1 = u1 * a1, gy1 = v1 * a1;
        const float gx2 = u2 * a2, gy2 = v2 * a2;
        const float gx3 = u3 * a3, gy3 = v3 * a3;

        const float D0x = gx2 - gx1, D0y = gy2 - gy1, D0z = d2 - d1;
        const float D1x = gx3 - gx1, D1y = gy3 - gy1, D1z = d3 - d1;
        const float D2x = gx3 - gx2, D2y = gy3 - gy2, D2z = d3 - d2;

        const float e00 = D0x*D0x + D0y*D0y + D0z*D0z;
        const float e11 = D1x*D1x + D1y*D1y + D1z*D1z;
        const float e22 = D2x*D2x + D2y*D2y + D2z*D2z;
        const float e01 = D0x*D1x + D0y*D1y + D0z*D1z;
        const float e02 = D0x*D2x + D0y*D2y + D0z*D2z;
        const float e12 = D1x*D2x + D1y*D2y + D1z*D2z;
        const float n0 = sqrtf(e00), n1 = sqrtf(e11), n2 = sqrtf(e22);
        constexpr float DC = 0.867f;
        int cnt = 0;
        cnt += (fabsf(e00) > DC * (n0*n0 + 1e-8f));
        cnt += (fabsf(e11) > DC * (n1*n1 + 1e-8f));
        cnt += (fabsf(e22) > DC * (n2*n2 + 1e-8f));
        cnt += 2 * (fabsf(e01) > DC * (n0*n1 + 1e-8f));
        cnt += 2 * (fabsf(e02) > DC * (n0*n2 + 1e-8f));
        cnt += 2 * (fabsf(e12) > DC * (n1*n2 + 1e-8f));
        const bool mask_cos = cnt > 3;

        const bool mx = (fabsf(D0x) < 0.01f) | (fabsf(D1x) < 0.01f) | (fabsf(D2x) < 0.01f);
        const bool my = (fabsf(D0y) < 0.01f) | (fabsf(D1y) < 0.01f) | (fabsf(D2y) < 0.01f);
        const bool mz = (fabsf(D0z) < 0.01f) | (fabsf(D1z) < 0.01f) | (fabsf(D2z) < 0.01f);
        const bool mask = !((mx && my && mz) || mask_cos);

        const float b1s = fabsf(e1) * RF, b2s = fabsf(e2) * RF, b3s = fabsf(e3) * RF;
        float qx1 = u1 * b1s, qy1 = v1 * b1s, qz1 = e1;
        float qx2 = u2 * b2s, qy2 = v2 * b2s, qz2 = e2;
        float qx3 = u3 * b3s, qy3 = v3 * b3s, qz3 = e3;
        // reference's zmask broadcast: coordinate ROW c of all points
        const bool zm0 = (qz1 == 0.0f), zm1 = (qz2 == 0.0f), zm2 = (qz3 == 0.0f);
        if (zm0) { qx1 = qx2 = qx3 = 1e-4f; }
        if (zm1) { qy1 = qy2 = qy3 = 1e-4f; }
        if (zm2) { qz1 = qz2 = qz3 = 1e-4f; }

        const float P0x = qx2 - qx1, P0y = qy2 - qy1, P0z = qz2 - qz1;
        const float Q1x = qx3 - qx1, Q1y = qy3 - qy1, Q1z = qz3 - qz1;

        const float gnx = D0y * D1z - D0z * D1y;
        const float gny = D0z * D1x - D0x * D1z;
        const float gnz = D0x * D1y - D0y * D1x;
        const float dnx = P0y * Q1z - P0z * Q1y;
        const float dny = P0z * Q1x - P0x * Q1z;
        const float dnz = P0x * Q1y - P0y * Q1x;

        float gnn = sqrtf(gnx*gnx + gny*gny + gnz*gnz);
        float dnn = sqrtf(dnx*dnx + dny*dny + dnz*dnz);
        if (gnn == 0.0f) gnn = 0.01f;
        if (dnn == 0.0f) dnn = 0.01f;
        const float rg = 1.0f / gnn, rd = 1.0f / dnn;
        const float L = fabsf(gnx*rg - dnx*rd) + fabsf(gny*rg - dny*rd) + fabsf(gnz*rg - dnz*rd);

        Lm[b * Gd + g] = mask ? L : -1.0f;
        if (mask) {
            ++lcnt;
            lsum += (double)L;
            atomicAdd(&lh[__float_as_uint(L) >> 20], 1u);
        }
    }

    // block reduction: wave shuffle, then 1 global atomic pair
#pragma unroll
    for (int off = 32; off > 0; off >>= 1) {
        lsum += __shfl_down(lsum, off);
        lcnt += __shfl_down(lcnt, off);
    }
    if ((t & 63) == 0) { wsum[t >> 6] = lsum; wcnt[t >> 6] = lcnt; }
    __syncthreads();
    if (t == 0) {
        atomicAdd((double*)(ws + WS_SUM_ALL), wsum[0] + wsum[1] + wsum[2] + wsum[3]);
        atomicAdd((unsigned*)(ws + WS_N), wcnt[0] + wcnt[1] + wcnt[2] + wcnt[3]);
    }
    unsigned* __restrict__ h1 = (unsigned*)(ws + HIST1_OFF);
    for (int k = t; k < 4096; k += 256) {
        const unsigned c = lh[k];
        if (c) atomicAdd(&h1[k], c);
    }

    // ---- fence-free completion: __syncthreads() drains vmcnt for every wave ----
    __syncthreads();
    if (t == 0) {
        const unsigned prev = __hip_atomic_fetch_add((unsigned*)(ws + WS_DONE1), 1u,
                                                     __ATOMIC_RELAXED, __HIP_MEMORY_SCOPE_AGENT);
        lastflag = (prev == (unsigned)(gridDim.x - 1));
    }
    __syncthreads();
    if (!lastflag) return;

    // ---- fused sel1 (last block only): select top-12-bit bin of drop-th smallest ----
    const unsigned n = __hip_atomic_load((const unsigned*)(ws + WS_N),
                                         __ATOMIC_RELAXED, __HIP_MEMORY_SCOPE_AGENT);
    const unsigned drop = n >> 2;
    if (t == 0) *(unsigned*)(ws + WS_DROP) = drop;
    if (drop == 0) {
        if (t == 0) { *(unsigned*)(ws + WS_BIN1) = 0xFFFFFFFFu; *(unsigned*)(ws + WS_TGT1) = 0u; }
        return;
    }
    unsigned loc[16]; unsigned s = 0;
#pragma unroll
    for (int k = 0; k < 16; ++k) {
        loc[k] = __hip_atomic_load(&h1[t * 16 + k], __ATOMIC_RELAXED, __HIP_MEMORY_SCOPE_AGENT);
        s += loc[k];
    }
    unsigned* part = lh;   // reuse LDS
    part[t] = s;
    __syncthreads();
    for (int off = 1; off < 256; off <<= 1) {
        const unsigned add = (t >= off) ? part[t - off] : 0u;
        __syncthreads();
        part[t] += add;
        __syncthreads();
    }
    const unsigned incl = part[t];
    const unsigned excl = incl - s;
    if (incl >= drop && excl < drop) {
        unsigned cum = excl;
#pragma unroll
        for (int k = 0; k < 16; ++k) {
            const unsigned c = loc[k];
            if (cum + c >= drop) {
                *(unsigned*)(ws + WS_BIN1) = (unsigned)(t * 16 + k);
                *(unsigned*)(ws + WS_TGT1) = drop - cum;
                break;
            }
            cum += c;
        }
    }
}

// ---------------- kernel 2: hist2 within bin1 + sum_less (+ fence-free fused finalize) ----------------
__global__ __launch_bounds__(256) void k_hist2(unsigned char* __restrict__ ws,
                                               float* __restrict__ out)
{
    __shared__ unsigned c2[4096];
    __shared__ float    s2[4096];
    __shared__ double   red[4];
    __shared__ double   ps[256];
    __shared__ int      lastflag;
    const int t = threadIdx.x;
    for (int k = t; k < 4096; k += 256) { c2[k] = 0u; s2[k] = 0.0f; }
    __syncthreads();

    const unsigned bin1 = *(const unsigned*)(ws + WS_BIN1);
    const uint4* __restrict__ Lm4 = (const uint4*)(ws + LM_OFF);
    const int n4 = Nd / 4;
    const int stride = gridDim.x * 256;
    double dless = 0.0;
    for (int i = blockIdx.x * 256 + t; i < n4; i += stride) {
        const uint4 q = Lm4[i];
        unsigned uu[4] = {q.x, q.y, q.z, q.w};
#pragma unroll
        for (int j = 0; j < 4; ++j) {
            const unsigned u = uu[j];
            if (u & 0x80000000u) continue;
            const unsigned top = u >> 20;
            if (top < bin1) {
                dless += (double)__uint_as_float(u);
            } else if (top == bin1) {
                const int k = (u >> 8) & 0xFFF;
                atomicAdd(&c2[k], 1u);
                atomicAdd(&s2[k], __uint_as_float(u));
            }
        }
    }
#pragma unroll
    for (int off = 32; off > 0; off >>= 1) dless += __shfl_down(dless, off);
    if ((t & 63) == 0) red[t >> 6] = dless;
    __syncthreads();
    if (t == 0) atomicAdd((double*)(ws + WS_SUM_LESS), red[0] + red[1] + red[2] + red[3]);

    unsigned* __restrict__ gc = (unsigned*)(ws + H2C_OFF);
    double*   __restrict__ gs = (double*)(ws + H2S_OFF);
    for (int k = t; k < 4096; k += 256) {
        const unsigned c = c2[k];
        if (c) { atomicAdd(&gc[k], c); atomicAdd(&gs[k], (double)s2[k]); }
    }

    // ---- fence-free completion ----
    __syncthreads();
    if (t == 0) {
        const unsigned prev = __hip_atomic_fetch_add((unsigned*)(ws + WS_DONE2), 1u,
                                                     __ATOMIC_RELAXED, __HIP_MEMORY_SCOPE_AGENT);
        lastflag = (prev == (unsigned)(gridDim.x - 1));
    }
    __syncthreads();
    if (!lastflag) return;

    const unsigned n    = *(const unsigned*)(ws + WS_N);
    const unsigned drop = *(const unsigned*)(ws + WS_DROP);
    const double sum_all = *(const double*)(ws + WS_SUM_ALL);
    const unsigned keep = n - drop;
    const double denom = (double)(keep > 0u ? keep : 1u);

    if (drop == 0) {
        if (t == 0) out[0] = (float)(sum_all / denom);
        return;
    }
    const unsigned tgt1 = *(const unsigned*)(ws + WS_TGT1);
    const double sum_less = __hip_atomic_load((const double*)(ws + WS_SUM_LESS),
                                              __ATOMIC_RELAXED, __HIP_MEMORY_SCOPE_AGENT);
    unsigned lc[16]; double lsv[16];
    unsigned cs = 0; double ss = 0.0;
#pragma unroll
    for (int k = 0; k < 16; ++k) {
        lc[k]  = __hip_atomic_load(&gc[t * 16 + k], __ATOMIC_RELAXED, __HIP_MEMORY_SCOPE_AGENT);
        lsv[k] = __hip_atomic_load(&gs[t * 16 + k], __ATOMIC_RELAXED, __HIP_MEMORY_SCOPE_AGENT);
        cs += lc[k]; ss += lsv[k];
    }
    unsigned* pc = c2;   // reuse LDS
    pc[t] = cs; ps[t] = ss;
    __syncthreads();
    for (int off = 1; off < 256; off <<= 1) {
        const unsigned addc = (t >= off) ? pc[t - off] : 0u;
        const double   adds = (t >= off) ? ps[t - off] : 0.0;
        __syncthreads();
        pc[t] += addc; ps[t] += adds;
        __syncthreads();
    }
    const unsigned inclc = pc[t];
    const unsigned exclc = inclc - cs;
    if (inclc >= tgt1 && exclc < tgt1) {
        unsigned cum = exclc;
        double scum = ps[t] - ss;
        for (int k = 0; k < 16; ++k) {
            const unsigned c = lc[k];
            if (cum + c >= tgt1) {
                const unsigned bin2 = (unsigned)(t * 16 + k);
                const unsigned tgt2 = tgt1 - cum;
                const float v_lo = __uint_as_float((bin1 << 20) | (bin2 << 8));
                const double dropped = sum_less + scum + (double)tgt2 * (double)v_lo;
                out[0] = (float)((sum_all - dropped) / denom);
                break;
            }
            cum += c;
            scum += lsv[k];
        }
    }
}

extern "C" void kernel_launch(void* const* d_in, const int* in_sizes, int n_in,
                              void* d_out, int out_size, void* d_ws, size_t ws_size,
                              hipStream_t stream)
{
    const float* gt  = (const float*)d_in[0];
    const float* pd  = (const float*)d_in[1];
    const int*   p1x = (const int*)d_in[2];
    const int*   p1y = (const int*)d_in[3];
    const int*   p2x = (const int*)d_in[4];
    const int*   p2y = (const int*)d_in[5];
    const int*   p3x = (const int*)d_in[6];
    const int*   p3y = (const int*)d_in[7];
    unsigned char* ws = (unsigned char*)d_ws;
    float* out = (float*)d_out;

    k_pack   <<<dim3(GRIDP), dim3(256), 0, stream>>>(gt, pd, ws);
    k_compute<<<dim3(GRIDC), dim3(256), 0, stream>>>(p1x, p1y, p2x, p2y, p3x, p3y, ws);
    k_hist2  <<<dim3(GRIDH), dim3(256), 0, stream>>>(ws, out);
}

// Round 6
// 160.512 us; speedup vs baseline: 1.6836x; 1.2516x over previous
//
#include <hip/hip_runtime.h>
#include <stdint.h>

// ---------------- problem constants ----------------
constexpr int Wd  = 640;
constexpr int Hd  = 480;
constexpr int Bd  = 8;
constexpr int Gd  = 368640;          // int(B*H*W*0.15)
constexpr int HWd = Hd * Wd;         // 307200
constexpr int GRIDP = HWd / 256;     // 1200
constexpr int GRIDC = Gd / 256;      // 1440

// ---------------- workspace layout (bytes) ----------------
#define WS_SUM_ALL  0      // double: sum of all masked L
#define WS_N        16     // u32: masked count
#define WS_DONE1    32     // u32: k_compute completion counter
#define HISTC_OFF   64                       // 4096 u32  (count per top-12-bit bin)
#define HISTS_OFF   (HISTC_OFF + 4096*4)     // 4096 double (value sum per bin)
#define CTRL_BYTES  (HISTS_OFF + 4096*8)     // 49216
#define CTRL_WORDS  (CTRL_BYTES / 4)
#define PACK_OFF    ((CTRL_BYTES + 255) & ~255)   // float pk[HWd][16], 64B/pixel

// ---------------- kernel 0: repack depth (pixel-major, batch-minor) + zero ctrl ----------------
__global__ __launch_bounds__(256) void k_pack(const float* __restrict__ gt,
                                              const float* __restrict__ pd,
                                              unsigned char* __restrict__ ws)
{
    const int o = blockIdx.x * 256 + threadIdx.x;
    float v[16];
#pragma unroll
    for (int b = 0; b < Bd; ++b) {
        v[2 * b]     = gt[b * HWd + o];
        v[2 * b + 1] = pd[b * HWd + o];
    }
    float4* __restrict__ dst = (float4*)(ws + PACK_OFF) + (size_t)o * 4;
#pragma unroll
    for (int c = 0; c < 4; ++c)
        dst[c] = make_float4(v[4 * c], v[4 * c + 1], v[4 * c + 2], v[4 * c + 3]);

    if (blockIdx.x == 0) {
        unsigned* __restrict__ ctrl = (unsigned*)ws;
        for (int k = threadIdx.x; k < CTRL_WORDS; k += 256) ctrl[k] = 0u;
    }
}

// ---------------- kernel 1: everything else, single pass ----------------
// Per-sample L + mask; LDS hist of {count,sum} over top-12-bit bins; block merge
// to global; fence-free last-block completion (no __threadfence — it thrashes
// the non-coherent per-XCD L2s, R3/R4 lesson: 73 -> 138 us); last block selects
// the drop-th smallest's bin via count prefix-scan, computes the dropped sum
// from exact per-bin sums + lower-edge approximation for the partial bin
// (error <= tgt1 * v * 2^-3 / denom ~ 1e-3, threshold 4.16e-2), writes out.
__global__ __launch_bounds__(256) void k_compute(
    const int* __restrict__ p1x, const int* __restrict__ p1y,
    const int* __restrict__ p2x, const int* __restrict__ p2y,
    const int* __restrict__ p3x, const int* __restrict__ p3y,
    unsigned char* __restrict__ ws, float* __restrict__ out)
{
    __shared__ unsigned lhc[4096];
    __shared__ float    lhs[4096];
    __shared__ double   wsum[4];
    __shared__ unsigned wcnt[4];
    __shared__ double   ps[256];
    __shared__ int      lastflag;
    const int t = threadIdx.x;
    for (int k = t; k < 4096; k += 256) { lhc[k] = 0u; lhs[k] = 0.0f; }
    __syncthreads();

    const int g = blockIdx.x * 256 + t;
    const int x1 = p1x[g], y1 = p1y[g];
    const int x2 = p2x[g], y2 = p2y[g];
    const int x3 = p3x[g], y3 = p3y[g];
    const int o1 = y1 * Wd + x1, o2 = y2 * Wd + x2, o3 = y3 * Wd + x3;
    const float u1 = (float)x1 - 320.0f, v1 = (float)y1 - 240.0f;
    const float u2 = (float)x2 - 320.0f, v2 = (float)y2 - 240.0f;
    const float u3 = (float)x3 - 320.0f, v3 = (float)y3 - 240.0f;
    constexpr float RF = 1.0f / 519.0f;

    // 3 random 64B lines, issued as 12 independent float4 loads (max MLP)
    const float4* __restrict__ pk4 = (const float4*)(ws + PACK_OFF);
    float4 A[4], Bv[4], Cv[4];
#pragma unroll
    for (int c = 0; c < 4; ++c) {
        A[c]  = pk4[(size_t)o1 * 4 + c];
        Bv[c] = pk4[(size_t)o2 * 4 + c];
        Cv[c] = pk4[(size_t)o3 * 4 + c];
    }
    const float* __restrict__ P1 = (const float*)A;
    const float* __restrict__ P2 = (const float*)Bv;
    const float* __restrict__ P3 = (const float*)Cv;

    double   lsum = 0.0;
    unsigned lcnt = 0u;

#pragma unroll
    for (int b = 0; b < Bd; ++b) {
        const float d1 = P1[2 * b], e1 = P1[2 * b + 1];
        const float d2 = P2[2 * b], e2 = P2[2 * b + 1];
        const float d3 = P3[2 * b], e3 = P3[2 * b + 1];

        const float a1 = fabsf(d1) * RF, a2 = fabsf(d2) * RF, a3 = fabsf(d3) * RF;
        const float gx1 = u1 * a1, gy1 = v1 * a1;
        const float gx2 = u2 * a2, gy2 = v2 * a2;
        const float gx3 = u3 * a3, gy3 = v3 * a3;

        const float D0x = gx2 - gx1, D0y = gy2 - gy1, D0z = d2 - d1;
        const float D1x = gx3 - gx1, D1y = gy3 - gy1, D1z = d3 - d1;
        const float D2x = gx3 - gx2, D2y = gy3 - gy2, D2z = d3 - d2;

        const float e00 = D0x*D0x + D0y*D0y + D0z*D0z;
        const float e11 = D1x*D1x + D1y*D1y + D1z*D1z;
        const float e22 = D2x*D2x + D2y*D2y + D2z*D2z;
        const float e01 = D0x*D1x + D0y*D1y + D0z*D1z;
        const float e02 = D0x*D2x + D0y*D2y + D0z*D2z;
        const float e12 = D1x*D2x + D1y*D2y + D1z*D2z;
        const float n0 = sqrtf(e00), n1 = sqrtf(e11), n2 = sqrtf(e22);
        constexpr float DC = 0.867f;
        int cnt = 0;
        cnt += (fabsf(e00) > DC * (n0*n0 + 1e-8f));
        cnt += (fabsf(e11) > DC * (n1*n1 + 1e-8f));
        cnt += (fabsf(e22) > DC * (n2*n2 + 1e-8f));
        cnt += 2 * (fabsf(e01) > DC * (n0*n1 + 1e-8f));
        cnt += 2 * (fabsf(e02) > DC * (n0*n2 + 1e-8f));
        cnt += 2 * (fabsf(e12) > DC * (n1*n2 + 1e-8f));
        const bool mask_cos = cnt > 3;

        const bool mx = (fabsf(D0x) < 0.01f) | (fabsf(D1x) < 0.01f) | (fabsf(D2x) < 0.01f);
        const bool my = (fabsf(D0y) < 0.01f) | (fabsf(D1y) < 0.01f) | (fabsf(D2y) < 0.01f);
        const bool mz = (fabsf(D0z) < 0.01f) | (fabsf(D1z) < 0.01f) | (fabsf(D2z) < 0.01f);
        const bool mask = !((mx && my && mz) || mask_cos);

        const float b1s = fabsf(e1) * RF, b2s = fabsf(e2) * RF, b3s = fabsf(e3) * RF;
        float qx1 = u1 * b1s, qy1 = v1 * b1s, qz1 = e1;
        float qx2 = u2 * b2s, qy2 = v2 * b2s, qz2 = e2;
        float qx3 = u3 * b3s, qy3 = v3 * b3s, qz3 = e3;
        // reference's zmask broadcast: coordinate ROW c of all points
        const bool zm0 = (qz1 == 0.0f), zm1 = (qz2 == 0.0f), zm2 = (qz3 == 0.0f);
        if (zm0) { qx1 = qx2 = qx3 = 1e-4f; }
        if (zm1) { qy1 = qy2 = qy3 = 1e-4f; }
        if (zm2) { qz1 = qz2 = qz3 = 1e-4f; }

        const float P0x = qx2 - qx1, P0y = qy2 - qy1, P0z = qz2 - qz1;
        const float Q1x = qx3 - qx1, Q1y = qy3 - qy1, Q1z = qz3 - qz1;

        const float gnx = D0y * D1z - D0z * D1y;
        const float gny = D0z * D1x - D0x * D1z;
        const float gnz = D0x * D1y - D0y * D1x;
        const float dnx = P0y * Q1z - P0z * Q1y;
        const float dny = P0z * Q1x - P0x * Q1z;
        const float dnz = P0x * Q1y - P0y * Q1x;

        float gnn = sqrtf(gnx*gnx + gny*gny + gnz*gnz);
        float dnn = sqrtf(dnx*dnx + dny*dny + dnz*dnz);
        if (gnn == 0.0f) gnn = 0.01f;
        if (dnn == 0.0f) dnn = 0.01f;
        const float rg = 1.0f / gnn, rd = 1.0f / dnn;
        const float L = fabsf(gnx*rg - dnx*rd) + fabsf(gny*rg - dny*rd) + fabsf(gnz*rg - dnz*rd);

        if (mask) {
            ++lcnt;
            lsum += (double)L;
            const unsigned bin = __float_as_uint(L) >> 20;
            atomicAdd(&lhc[bin], 1u);
            atomicAdd(&lhs[bin], L);
        }
    }

    // block reduction: wave shuffle, then 1 global atomic pair
#pragma unroll
    for (int off = 32; off > 0; off >>= 1) {
        lsum += __shfl_down(lsum, off);
        lcnt += __shfl_down(lcnt, off);
    }
    if ((t & 63) == 0) { wsum[t >> 6] = lsum; wcnt[t >> 6] = lcnt; }
    __syncthreads();
    if (t == 0) {
        atomicAdd((double*)(ws + WS_SUM_ALL), wsum[0] + wsum[1] + wsum[2] + wsum[3]);
        atomicAdd((unsigned*)(ws + WS_N), wcnt[0] + wcnt[1] + wcnt[2] + wcnt[3]);
    }
    unsigned* __restrict__ gc = (unsigned*)(ws + HISTC_OFF);
    double*   __restrict__ gs = (double*)(ws + HISTS_OFF);
    for (int k = t; k < 4096; k += 256) {
        const unsigned c = lhc[k];
        if (c) { atomicAdd(&gc[k], c); atomicAdd(&gs[k], (double)lhs[k]); }
    }

    // ---- fence-free completion: __syncthreads() drains vmcnt for every wave ----
    __syncthreads();
    if (t == 0) {
        const unsigned prev = __hip_atomic_fetch_add((unsigned*)(ws + WS_DONE1), 1u,
                                                     __ATOMIC_RELAXED, __HIP_MEMORY_SCOPE_AGENT);
        lastflag = (prev == (unsigned)(gridDim.x - 1));
    }
    __syncthreads();
    if (!lastflag) return;

    // ---- last block: select drop-th smallest bin, compute trimmed mean ----
    const unsigned n = __hip_atomic_load((const unsigned*)(ws + WS_N),
                                         __ATOMIC_RELAXED, __HIP_MEMORY_SCOPE_AGENT);
    const unsigned long long sa_bits =
        __hip_atomic_load((const unsigned long long*)(ws + WS_SUM_ALL),
                          __ATOMIC_RELAXED, __HIP_MEMORY_SCOPE_AGENT);
    const double sum_all = __longlong_as_double((long long)sa_bits);
    const unsigned drop = n >> 2;
    const unsigned keep = n - drop;
    const double denom = (double)(keep > 0u ? keep : 1u);

    if (drop == 0) {
        if (t == 0) out[0] = (float)(sum_all / denom);
        return;
    }

    unsigned lc[16]; double lsv[16];
    unsigned cs = 0; double ss = 0.0;
#pragma unroll
    for (int k = 0; k < 16; ++k) {
        lc[k] = __hip_atomic_load(&gc[t * 16 + k], __ATOMIC_RELAXED, __HIP_MEMORY_SCOPE_AGENT);
        const unsigned long long sb =
            __hip_atomic_load((const unsigned long long*)&gs[t * 16 + k],
                              __ATOMIC_RELAXED, __HIP_MEMORY_SCOPE_AGENT);
        lsv[k] = __longlong_as_double((long long)sb);
        cs += lc[k]; ss += lsv[k];
    }
    unsigned* pc = lhc;   // reuse LDS
    pc[t] = cs; ps[t] = ss;
    __syncthreads();
    for (int off = 1; off < 256; off <<= 1) {
        const unsigned addc = (t >= off) ? pc[t - off] : 0u;
        const double   adds = (t >= off) ? ps[t - off] : 0.0;
        __syncthreads();
        pc[t] += addc; ps[t] += adds;
        __syncthreads();
    }
    const unsigned inclc = pc[t];
    const unsigned exclc = inclc - cs;
    if (inclc >= drop && exclc < drop) {
        unsigned cum = exclc;
        double scum = ps[t] - ss;   // exact sum of all bins before this thread's chunk
        for (int k = 0; k < 16; ++k) {
            const unsigned c = lc[k];
            if (cum + c >= drop) {
                const unsigned bin1 = (unsigned)(t * 16 + k);
                const unsigned tgt1 = drop - cum;            // items taken inside bin1
                const float v_lo = __uint_as_float(bin1 << 20);  // bin lower edge
                const double dropped = scum + (double)tgt1 * (double)v_lo;
                out[0] = (float)((sum_all - dropped) / denom);
                break;
            }
            cum += c;
            scum += lsv[k];
        }
    }
}

extern "C" void kernel_launch(void* const* d_in, const int* in_sizes, int n_in,
                              void* d_out, int out_size, void* d_ws, size_t ws_size,
                              hipStream_t stream)
{
    const float* gt  = (const float*)d_in[0];
    const float* pd  = (const float*)d_in[1];
    const int*   p1x = (const int*)d_in[2];
    const int*   p1y = (const int*)d_in[3];
    const int*   p2x = (const int*)d_in[4];
    const int*   p2y = (const int*)d_in[5];
    const int*   p3x = (const int*)d_in[6];
    const int*   p3y = (const int*)d_in[7];
    unsigned char* ws = (unsigned char*)d_ws;
    float* out = (float*)d_out;

    k_pack   <<<dim3(GRIDP), dim3(256), 0, stream>>>(gt, pd, ws);
    k_compute<<<dim3(GRIDC), dim3(256), 0, stream>>>(p1x, p1y, p2x, p2y, p3x, p3y, ws, out);
}